// Round 7
// baseline (109.517 us; speedup 1.0000x reference)
//
#include <hip/hip_runtime.h>
#include <hip/hip_fp16.h>
#include <math.h>

// N=1024, C=128, H=4, HD=32, HID=64
//   u[n,m]   = pos[n,:] @ W1[:,m]       (hid[i,j,m] = (u[i,m]+b1[m]) - u[j,m])
//   A[n,h,m] = sum_d q[n,h*32+d] * W2[m, h*32+d]
//   c[n,h]   = sum_d q[n,h*32+d] * b2[h*32+d]
//   score[h,i,j] = (q_i.k_j)/sqrt(32) + sum_m relu(hid)*A[i,h,m] + c[i,h] - dist(i,j)
//   softmax via exp2 (q pre-scaled RS*log2e; A/c/pos pre-scaled log2e)
//
// R17 = R16 (108.6 us) + geom/qk loop MERGE: both phases are 8 iterations
//   and data-independent until exp; one loop issues 3 uint4 loads per iter
//   (u-word + 2 k-words) followed by ~90 mixed VALU ops -> ~2x memory- and
//   instruction-level parallelism in the score phase. Math bit-identical.
//   (R16 post-mortem: kernel is load-LATENCY bound; widening 64->40 load
//   batches gave -5.5 us. This attacks the serial phase structure.)
//
// ws layout (floats):
//   qT   u32[1024][64] f16x2 pairs                     @ 0
//   vJ   u32[512][128]: f16x2 (v[2jp][c], v[2jp+1][c]) @ 131072
//   kT8  u32[8][1024][8]: f16x2 k quads grouped        @ 262144
//   uT4  u32[8][1024][4]: bf16x2 u quads grouped       @ 327680
//   sA   [1024][328]                                   @ 360448
//   pos4 [1024][4] (x L2E)                             @ 696320

typedef float v2f __attribute__((ext_vector_type(2)));
typedef float v4f __attribute__((ext_vector_type(4)));
typedef __fp16 h2f __attribute__((ext_vector_type(2)));

#define L2E 1.4426950408889634f
#define RSL (0.17677669529663687f * L2E)

static __device__ __forceinline__ float dot4(float4 a, float4 b) {
  return a.x*b.x + a.y*b.y + a.z*b.z + a.w*b.w;
}
static __device__ __forceinline__ v2f fma2(v2f a, v2f b, v2f c) {
  return __builtin_elementwise_fma(a, b, c);
}
static __device__ __forceinline__ unsigned int bfr(float f) {   // fp32 -> bf16 (RNE)
  unsigned int b = __float_as_uint(f);
  return (b + 0x7fffu + ((b >> 16) & 1u)) >> 16;
}
static __device__ __forceinline__ unsigned int pack2(float lo, float hi) {
  return bfr(lo) | (bfr(hi) << 16);
}
static __device__ __forceinline__ v2f unpk(unsigned int a) {    // bf16x2 -> 2x fp32
  v2f r;
  r.x = __uint_as_float(a << 16);
  r.y = __uint_as_float(a & 0xffff0000u);
  return r;
}
static __device__ __forceinline__ unsigned int pkh(float lo, float hi) { // f16x2 (RTZ)
  h2f r = __builtin_amdgcn_cvt_pkrtz(lo, hi);
  return __builtin_bit_cast(unsigned int, r);
}
static __device__ __forceinline__ unsigned int pkrn(float lo, float hi) { // f16x2 (RNE)
  unsigned int a = (unsigned int)__half_as_ushort(__float2half(lo));
  unsigned int b = (unsigned int)__half_as_ushort(__float2half(hi));
  return a | (b << 16);
}
static __device__ __forceinline__ float fdot2h(unsigned int a_, unsigned int b_, float acc) {
  return __builtin_amdgcn_fdot2(__builtin_bit_cast(h2f, a_),
                                __builtin_bit_cast(h2f, b_), acc, false);
}
static __device__ __forceinline__ float r2hf(float x) { // round f32 to f16-representable
  h2f t = __builtin_amdgcn_cvt_pkrtz(x, x);
  return (float)t.x;
}

// ---------------- K1: precompute ------------------------------------------
// 512 blocks x 384 thr; block = 2 rows.
__global__ __launch_bounds__(384) void k_pre(
    const float* __restrict__ x, const float* __restrict__ y, const float* __restrict__ pos,
    const float* __restrict__ Wq, const float* __restrict__ bq,
    const float* __restrict__ Wk, const float* __restrict__ bk,
    const float* __restrict__ Wv, const float* __restrict__ bv,
    const float* __restrict__ W1, const float* __restrict__ b1,
    const float* __restrict__ W2, const float* __restrict__ b2,
    unsigned int* __restrict__ qT, unsigned int* __restrict__ vJ,
    unsigned int* __restrict__ kT8, unsigned int* __restrict__ uT4,
    float* __restrict__ sA, float* __restrict__ pos4w)
{
  __shared__ float xs[256], ys[256], qs[256];
  __shared__ __align__(16) float4 W2S[64*33];

  const int t  = threadIdx.x;
  const int n0 = blockIdx.x * 2;

  if (t < 256) { xs[t] = x[n0*128 + t]; ys[t] = y[n0*128 + t]; }
  {
    const float4* w2g = (const float4*)W2;
    #pragma unroll
    for (int r = 0; r < 6; ++r) {
      const int e = t + 384*r;
      if (e < 2048) W2S[(e>>5)*33 + (e&31)] = w2g[e];
    }
  }
  __syncthreads();

  {
    const int c   = t & 127;
    const int mat = t >> 7;                 // wave-uniform
    const float* W    = (mat == 0) ? Wq : (mat == 1 ? Wk : Wv);
    const float* S    = (mat == 0) ? xs : ys;
    const float* bias = (mat == 0) ? bq : (mat == 1 ? bk : bv);
    float a0 = 0.f, a1 = 0.f;
    #pragma unroll 8
    for (int d = 0; d < 128; ++d) {
      const float w_ = W[d*128 + c];
      a0 = fmaf(S[d],       w_, a0);
      a1 = fmaf(S[128 + d], w_, a1);
    }
    const float bb = bias[c];
    a0 += bb; a1 += bb;
    if (mat == 0) {
      qs[c] = a0; qs[128 + c] = a1;
      // q: pack adjacent columns into f16x2 pairs (pre-scaled by RSL)
      const float sa0 = a0 * RSL, sa1 = a1 * RSL;
      const float tb0 = __shfl_xor(sa0, 1);
      const float tb1 = __shfl_xor(sa1, 1);
      if ((c & 1) == 0) {
        qT[(n0  )*64 + (c>>1)] = pkh(sa0, tb0);
        qT[(n0+1)*64 + (c>>1)] = pkh(sa1, tb1);
      }
    } else if (mat == 2) {
      // v: pack the two rows (n0, n0+1) per column -> f16x2 (RNE)
      vJ[(n0>>1)*128 + c] = pkrn(a0, a1);
    } else {
      // k: pack adjacent columns via in-wave exchange; grouped layout:
      // kT8[(cb*1024 + n)*8 + slot*2 + wrd], qi=c>>2, cb=qi&7, slot=qi>>3
      const float b0 = __shfl_xor(a0, 1);
      const float b1 = __shfl_xor(a1, 1);
      if ((c & 1) == 0) {
        const int qi = c >> 2, cbv = qi & 7, slot = qi >> 3, wrd = (c >> 1) & 1;
        const int base = (cbv*1024 + n0)*8 + slot*2 + wrd;
        kT8[base]     = pkh(a0, b0);
        kT8[base + 8] = pkh(a1, b1);
      }
    }
  }
  __syncthreads();

  if (t < 256) {
    const int m = t & 63, h = t >> 6;
    const float4* qs4 = (const float4*)qs;
    #pragma unroll
    for (int ii = 0; ii < 2; ++ii) {
      float acc = 0.f;
      #pragma unroll
      for (int ch = 0; ch < 8; ++ch)
        acc += dot4(qs4[ii*32 + h*8 + ch], W2S[m*33 + h*8 + ch]);
      sA[(n0+ii)*328 + 8 + (m>>2)*20 + h*4 + (m&3)] = acc * L2E;
    }
    if (t < 8) {
      const int ii = t >> 2, h2 = t & 3;
      float ca = 0.f;
      #pragma unroll
      for (int d = 0; d < 32; ++d) ca = fmaf(qs[ii*128 + h2*32 + d], b2[h2*32 + d], ca);
      sA[(n0+ii)*328 + h2] = ca * L2E;
    } else if (t < 16) {
      const int tt = t-8, ii = tt>>2, cc = tt&3;
      sA[(n0+ii)*328 + 4 + cc] = (cc < 3) ? pos[(n0+ii)*3 + cc] * L2E : 0.f;
    } else if (t < 24) {
      const int tt = t-16, ii = tt>>2, cc = tt&3;
      pos4w[(n0+ii)*4 + cc] = (cc < 3) ? pos[(n0+ii)*3 + cc] * L2E : 0.f;
    }
  } else if (t < 320) {
    // u: thread = (ii, m-pair); grouped layout: uT4[((mp>>2)*1024 + n)*4 + (mp&3)]
    const int tt = t - 256, ii = tt >> 5, mp = tt & 31;
    const int m0 = mp * 2;
    float ua0 = 0.f, ua1 = 0.f;
    #pragma unroll
    for (int cc = 0; cc < 3; ++cc) {
      const float p = pos[(n0+ii)*3 + cc];
      ua0 = fmaf(p, W1[cc*64 + m0    ], ua0);
      ua1 = fmaf(p, W1[cc*64 + m0 + 1], ua1);
    }
    sA[(n0+ii)*328 + 8 + (m0>>2)*20 + 16 + (m0&3)    ] = ua0 + b1[m0];
    sA[(n0+ii)*328 + 8 + (m0>>2)*20 + 16 + (m0&3) + 1] = ua1 + b1[m0+1];
    uT4[((mp>>2)*1024 + (n0+ii))*4 + (mp&3)] = pack2(ua0, ua1);
  }
}

// ---------------- K2: fused scores + softmax + PV + direct out -------------
// 512 blocks x 1024 thr (16 waves). Block = 2 i-rows x ALL j; wave w = j-tile w.
__global__ __launch_bounds__(1024, 8) void k_attn(
    const unsigned int* __restrict__ qT, const unsigned int* __restrict__ vJ,
    const unsigned int* __restrict__ kT8, const unsigned int* __restrict__ uT4,
    const float* __restrict__ sA, const v4f* __restrict__ pos4,
    float* __restrict__ out)
{
  __shared__ __align__(16) float eL[16*544];   // per-wave E: [(ii*4+h)*68 + j]
  __shared__ __align__(16) float rnum[8192];   // v4f [w][ii][rep][c4]
  __shared__ float rden[128];                  // [w][ii*4+h]

  const int t     = threadIdx.x;
  const int i0    = blockIdx.x * 2;
  const int w     = t >> 6;                    // 0..15 = j-tile
  const int lane  = t & 63;
  const int c4    = lane & 31;
  const int rep   = lane >> 5;
  const int hh    = c4 >> 3;

  const int jb = w*64;
  const int j  = jb + lane;

  const float* sA0 = sA + i0*328;              // uniform -> scalar loads
  const float* sA1 = sA0 + 328;

  const float c00 = sA0[0], c01 = sA0[1], c02 = sA0[2], c03 = sA0[3];
  const float c10 = sA1[0], c11 = sA1[1], c12 = sA1[2], c13 = sA1[3];
  const float p0x = sA0[4], p0y = sA0[5], p0z = sA0[6];
  const float p1x = sA1[4], p1y = sA1[5], p1z = sA1[6];

  const v4f pj = pos4[j];
  const float d0x = p0x-pj.x, d0y = p0y-pj.y, d0z = p0z-pj.z;
  const float d1x = p1x-pj.x, d1y = p1y-pj.y, d1z = p1z-pj.z;
  const float dist0 = sqrtf(d0x*d0x + d0y*d0y + d0z*d0z);
  const float dist1 = sqrtf(d1x*d1x + d1y*d1y + d1z*d1z);

  // ---- merged geom + qk loop: 3 independent uint4 loads per iter, then
  //      ~90 mixed pk-fma / dot2 ops. geom accumulates into g*, qk into t*.
  v2f g0a={0.f,0.f}, g0b={0.f,0.f}, g0c={0.f,0.f}, g0d={0.f,0.f};
  v2f g1a={0.f,0.f}, g1b={0.f,0.f}, g1c={0.f,0.f}, g1d={0.f,0.f};
  float t0a=0.f, t0b=0.f, t0c=0.f, t0d=0.f;
  float t1a=0.f, t1b=0.f, t1c=0.f, t1d=0.f;
  {
    const uint4* ug = (const uint4*)uT4;
    const uint4* kg = (const uint4*)kT8;
    const unsigned int* qT0 = qT + i0*64;
    const unsigned int* qT1 = qT0 + 64;
#define GEOM_MB(MB, W01, W23) { \
    const v2f uj01 = unpk(W01), uj23 = unpk(W23); \
    const v2f z = {0.f, 0.f}; \
    { \
      const float* ab = sA0 + 8 + (MB)*20; \
      const v2f h01 = __builtin_elementwise_max(*(const v2f*)(ab+16) - uj01, z); \
      const v2f h23 = __builtin_elementwise_max(*(const v2f*)(ab+18) - uj23, z); \
      g0a = fma2(h01, *(const v2f*)(ab+ 0), g0a); g0a = fma2(h23, *(const v2f*)(ab+ 2), g0a); \
      g0b = fma2(h01, *(const v2f*)(ab+ 4), g0b); g0b = fma2(h23, *(const v2f*)(ab+ 6), g0b); \
      g0c = fma2(h01, *(const v2f*)(ab+ 8), g0c); g0c = fma2(h23, *(const v2f*)(ab+10), g0c); \
      g0d = fma2(h01, *(const v2f*)(ab+12), g0d); g0d = fma2(h23, *(const v2f*)(ab+14), g0d); \
    } \
    { \
      const float* ab = sA1 + 8 + (MB)*20; \
      const v2f h01 = __builtin_elementwise_max(*(const v2f*)(ab+16) - uj01, z); \
      const v2f h23 = __builtin_elementwise_max(*(const v2f*)(ab+18) - uj23, z); \
      g1a = fma2(h01, *(const v2f*)(ab+ 0), g1a); g1a = fma2(h23, *(const v2f*)(ab+ 2), g1a); \
      g1b = fma2(h01, *(const v2f*)(ab+ 4), g1b); g1b = fma2(h23, *(const v2f*)(ab+ 6), g1b); \
      g1c = fma2(h01, *(const v2f*)(ab+ 8), g1c); g1c = fma2(h23, *(const v2f*)(ab+10), g1c); \
      g1d = fma2(h01, *(const v2f*)(ab+12), g1d); g1d = fma2(h23, *(const v2f*)(ab+14), g1d); \
    } \
  }
    #pragma unroll 2
    for (int g = 0; g < 8; ++g) {
      const uint4 uw = ug[g*1024 + j];
      const uint4 ka = kg[(g*1024 + j)*2];
      const uint4 kb = kg[(g*1024 + j)*2 + 1];
      GEOM_MB(2*g,     uw.x, uw.y)
      GEOM_MB(2*g + 1, uw.z, uw.w)
      t0a = fdot2h(ka.x, qT0[     g*2], t0a); t0a = fdot2h(ka.y, qT0[     g*2+1], t0a);
      t0b = fdot2h(ka.z, qT0[16 + g*2], t0b); t0b = fdot2h(ka.w, qT0[16 + g*2+1], t0b);
      t0c = fdot2h(kb.x, qT0[32 + g*2], t0c); t0c = fdot2h(kb.y, qT0[32 + g*2+1], t0c);
      t0d = fdot2h(kb.z, qT0[48 + g*2], t0d); t0d = fdot2h(kb.w, qT0[48 + g*2+1], t0d);
      t1a = fdot2h(ka.x, qT1[     g*2], t1a); t1a = fdot2h(ka.y, qT1[     g*2+1], t1a);
      t1b = fdot2h(ka.z, qT1[16 + g*2], t1b); t1b = fdot2h(ka.w, qT1[16 + g*2+1], t1b);
      t1c = fdot2h(kb.x, qT1[32 + g*2], t1c); t1c = fdot2h(kb.y, qT1[32 + g*2+1], t1c);
      t1d = fdot2h(kb.z, qT1[48 + g*2], t1d); t1d = fdot2h(kb.w, qT1[48 + g*2+1], t1d);
    }
#undef GEOM_MB
  }

  // combine geom into qk scalars
  const float s0a = t0a + g0a.x + g0a.y, s0b = t0b + g0b.x + g0b.y;
  const float s0c = t0c + g0c.x + g0c.y, s0d = t0d + g0d.x + g0d.y;
  const float s1a = t1a + g1a.x + g1a.y, s1b = t1b + g1b.x + g1b.y;
  const float s1c = t1c + g1c.x + g1c.y, s1d = t1d + g1d.x + g1d.y;

  // ---- exp2 numerators (rounded to f16-representable) -> wave-private E ----
  float lsum[8];
  float* eW = &eL[w*544];
  {
    const float p0 = r2hf(exp2f(s0a + (c00 - dist0)));
    const float p1 = r2hf(exp2f(s0b + (c01 - dist0)));
    const float p2 = r2hf(exp2f(s0c + (c02 - dist0)));
    const float p3 = r2hf(exp2f(s0d + (c03 - dist0)));
    lsum[0] = p0; lsum[1] = p1; lsum[2] = p2; lsum[3] = p3;
    eW[      lane] = p0; eW[ 68 + lane] = p1; eW[136 + lane] = p2; eW[204 + lane] = p3;
    const float r0 = r2hf(exp2f(s1a + (c10 - dist1)));
    const float r1 = r2hf(exp2f(s1b + (c11 - dist1)));
    const float r2 = r2hf(exp2f(s1c + (c12 - dist1)));
    const float r3 = r2hf(exp2f(s1d + (c13 - dist1)));
    lsum[4] = r0; lsum[5] = r1; lsum[6] = r2; lsum[7] = r3;
    eW[272 + lane] = r0; eW[340 + lane] = r1; eW[408 + lane] = r2; eW[476 + lane] = r3;
  }
  __builtin_amdgcn_wave_barrier();

  // ---- denominator reduce first (frees lsum before PV raises pressure) ----
  #pragma unroll
  for (int mm = 1; mm < 64; mm <<= 1) {
    #pragma unroll
    for (int r8 = 0; r8 < 8; ++r8) lsum[r8] += __shfl_xor(lsum[r8], mm);
  }
  if (lane == 0) {
    #pragma unroll
    for (int r8 = 0; r8 < 8; ++r8) rden[w*8 + r8] = lsum[r8];
  }

  // ---- PV: lane owns col-quad c4 (head hh), rep = jp-half of tile.
  //      v is f16x2 over j-pairs; e pairs packed in-lane (exact: pre-rounded) ----
  v4f acc0 = {0.f,0.f,0.f,0.f};
  v4f acc1 = {0.f,0.f,0.f,0.f};
  {
    const float* er0 = &eL[w*544 +  hh   *68 + rep*32];
    const float* er1 = &eL[w*544 + (4+hh)*68 + rep*32];
    const uint4* vg = (const uint4*)vJ + (w*32 + rep*16)*32 + c4;
    #pragma unroll 4
    for (int m = 0; m < 16; ++m) {
      const uint4 vw = vg[m*32];
      const unsigned int e0 = pkh(er0[2*m], er0[2*m+1]);
      const unsigned int e1 = pkh(er1[2*m], er1[2*m+1]);
      acc0.x = fdot2h(vw.x, e0, acc0.x); acc0.y = fdot2h(vw.y, e0, acc0.y);
      acc0.z = fdot2h(vw.z, e0, acc0.z); acc0.w = fdot2h(vw.w, e0, acc0.w);
      acc1.x = fdot2h(vw.x, e1, acc1.x); acc1.y = fdot2h(vw.y, e1, acc1.y);
      acc1.z = fdot2h(vw.z, e1, acc1.z); acc1.w = fdot2h(vw.w, e1, acc1.w);
    }
  }
  __builtin_amdgcn_wave_barrier();

  // ---- in-block reduce across 16 waves ----
  ((v4f*)rnum)[((w*2+0)*2 + rep)*32 + c4] = acc0;
  ((v4f*)rnum)[((w*2+1)*2 + rep)*32 + c4] = acc1;
  __syncthreads();

  if (t < 256) {
    const int ii = t >> 7, c = t & 127;
    float num = 0.f, den = 0.f;
    #pragma unroll
    for (int ww = 0; ww < 16; ++ww) {
      num += rnum[((ww*2+ii)*2+0)*128 + c];
      num += rnum[((ww*2+ii)*2+1)*128 + c];
      den += rden[ww*8 + ii*4 + (c>>5)];
    }
    out[(i0+ii)*128 + c] = num / den;
  }
}

extern "C" void kernel_launch(void* const* d_in, const int* in_sizes, int n_in,
                              void* d_out, int out_size, void* d_ws, size_t ws_size,
                              hipStream_t stream) {
  const float* x   = (const float*)d_in[0];
  const float* y   = (const float*)d_in[1];
  const float* pos = (const float*)d_in[2];
  const float* Wq  = (const float*)d_in[3];
  const float* bq  = (const float*)d_in[4];
  const float* Wk  = (const float*)d_in[5];
  const float* bk  = (const float*)d_in[6];
  const float* Wv  = (const float*)d_in[7];
  const float* bv  = (const float*)d_in[8];
  const float* W1  = (const float*)d_in[9];
  const float* b1  = (const float*)d_in[10];
  const float* W2  = (const float*)d_in[11];
  const float* b2  = (const float*)d_in[12];

  float* ws = (float*)d_ws;
  unsigned int* qT   = (unsigned int*)ws;               // 65536 u32 (region 131072 f)
  unsigned int* vJ   = (unsigned int*)(ws + 131072);    // 65536 u32 (region 131072 f)
  unsigned int* kT8  = (unsigned int*)(ws + 262144);    // 65536 u32
  unsigned int* uT4  = (unsigned int*)(ws + 327680);    // 32768 u32
  float*        sA   = ws + 360448;                     // 335872
  float*        pos4 = ws + 696320;                     // 4096
  float*        out  = (float*)d_out;

  k_pre<<<dim3(512), dim3(384), 0, stream>>>(x, y, pos, Wq, bq, Wk, bk, Wv, bv,
                                             W1, b1, W2, b2,
                                             qT, vJ, kT8, uT4, sA, pos4);
  k_attn<<<dim3(512), dim3(1024), 0, stream>>>(qT, vJ, kT8, uT4, sA,
                                               (const v4f*)pos4, out);
}

// Round 8
// 108.501 us; speedup vs baseline: 1.0094x; 1.0094x over previous
//
#include <hip/hip_runtime.h>
#include <hip/hip_fp16.h>
#include <math.h>

// N=1024, C=128, H=4, HD=32, HID=64
//   u[n,m]   = pos[n,:] @ W1[:,m]       (hid[i,j,m] = (u[i,m]+b1[m]) - u[j,m])
//   A[n,h,m] = sum_d q[n,h*32+d] * W2[m, h*32+d]
//   c[n,h]   = sum_d q[n,h*32+d] * b2[h*32+d]
//   score[h,i,j] = (q_i.k_j)/sqrt(32) + sum_m relu(hid)*A[i,h,m] + c[i,h] - dist(i,j)
//   softmax via exp2 (q pre-scaled RS*log2e; A/c/pos pre-scaled log2e)
//
// R18 = R16 (108.6 us; R17's geom/qk merge was neutral -> reverted) + e
//   stored in LDS as f16 BITS via 16-bit writes (eH ushort rows). PV reads
//   packed f16x2 words directly: -32 cvt_pkrtz per thread in PV, half the
//   PV LDS read bytes. Math bit-identical to R16 (same RTZ-rounded e feeds
//   num and den).
//
// ws layout (floats):
//   qT   u32[1024][64] f16x2 pairs                     @ 0
//   vJ   u32[512][128]: f16x2 (v[2jp][c], v[2jp+1][c]) @ 131072
//   kT8  u32[8][1024][8]: f16x2 k quads grouped        @ 262144
//   uT4  u32[8][1024][4]: bf16x2 u quads grouped       @ 327680
//   sA   [1024][328]                                   @ 360448
//   pos4 [1024][4] (x L2E)                             @ 696320

typedef float v2f __attribute__((ext_vector_type(2)));
typedef float v4f __attribute__((ext_vector_type(4)));
typedef __fp16 h2f __attribute__((ext_vector_type(2)));

#define L2E 1.4426950408889634f
#define RSL (0.17677669529663687f * L2E)

static __device__ __forceinline__ float dot4(float4 a, float4 b) {
  return a.x*b.x + a.y*b.y + a.z*b.z + a.w*b.w;
}
static __device__ __forceinline__ v2f fma2(v2f a, v2f b, v2f c) {
  return __builtin_elementwise_fma(a, b, c);
}
static __device__ __forceinline__ unsigned int bfr(float f) {   // fp32 -> bf16 (RNE)
  unsigned int b = __float_as_uint(f);
  return (b + 0x7fffu + ((b >> 16) & 1u)) >> 16;
}
static __device__ __forceinline__ unsigned int pack2(float lo, float hi) {
  return bfr(lo) | (bfr(hi) << 16);
}
static __device__ __forceinline__ v2f unpk(unsigned int a) {    // bf16x2 -> 2x fp32
  v2f r;
  r.x = __uint_as_float(a << 16);
  r.y = __uint_as_float(a & 0xffff0000u);
  return r;
}
static __device__ __forceinline__ unsigned int pkh(float lo, float hi) { // f16x2 (RTZ)
  h2f r = __builtin_amdgcn_cvt_pkrtz(lo, hi);
  return __builtin_bit_cast(unsigned int, r);
}
static __device__ __forceinline__ unsigned int pkrn(float lo, float hi) { // f16x2 (RNE)
  unsigned int a = (unsigned int)__half_as_ushort(__float2half(lo));
  unsigned int b = (unsigned int)__half_as_ushort(__float2half(hi));
  return a | (b << 16);
}
static __device__ __forceinline__ float fdot2h(unsigned int a_, unsigned int b_, float acc) {
  return __builtin_amdgcn_fdot2(__builtin_bit_cast(h2f, a_),
                                __builtin_bit_cast(h2f, b_), acc, false);
}
// round x to f16 (RTZ): store the 16 bits to *dst, return rounded value as f32
static __device__ __forceinline__ float e16(float x, unsigned short* dst) {
  unsigned int pb = pkh(x, x);
  *dst = (unsigned short)pb;
  return (float)__builtin_bit_cast(h2f, pb).x;
}

// ---------------- K1: precompute ------------------------------------------
// 512 blocks x 384 thr; block = 2 rows.
__global__ __launch_bounds__(384) void k_pre(
    const float* __restrict__ x, const float* __restrict__ y, const float* __restrict__ pos,
    const float* __restrict__ Wq, const float* __restrict__ bq,
    const float* __restrict__ Wk, const float* __restrict__ bk,
    const float* __restrict__ Wv, const float* __restrict__ bv,
    const float* __restrict__ W1, const float* __restrict__ b1,
    const float* __restrict__ W2, const float* __restrict__ b2,
    unsigned int* __restrict__ qT, unsigned int* __restrict__ vJ,
    unsigned int* __restrict__ kT8, unsigned int* __restrict__ uT4,
    float* __restrict__ sA, float* __restrict__ pos4w)
{
  __shared__ float xs[256], ys[256], qs[256];
  __shared__ __align__(16) float4 W2S[64*33];

  const int t  = threadIdx.x;
  const int n0 = blockIdx.x * 2;

  if (t < 256) { xs[t] = x[n0*128 + t]; ys[t] = y[n0*128 + t]; }
  {
    const float4* w2g = (const float4*)W2;
    #pragma unroll
    for (int r = 0; r < 6; ++r) {
      const int e = t + 384*r;
      if (e < 2048) W2S[(e>>5)*33 + (e&31)] = w2g[e];
    }
  }
  __syncthreads();

  {
    const int c   = t & 127;
    const int mat = t >> 7;                 // wave-uniform
    const float* W    = (mat == 0) ? Wq : (mat == 1 ? Wk : Wv);
    const float* S    = (mat == 0) ? xs : ys;
    const float* bias = (mat == 0) ? bq : (mat == 1 ? bk : bv);
    float a0 = 0.f, a1 = 0.f;
    #pragma unroll 8
    for (int d = 0; d < 128; ++d) {
      const float w_ = W[d*128 + c];
      a0 = fmaf(S[d],       w_, a0);
      a1 = fmaf(S[128 + d], w_, a1);
    }
    const float bb = bias[c];
    a0 += bb; a1 += bb;
    if (mat == 0) {
      qs[c] = a0; qs[128 + c] = a1;
      // q: pack adjacent columns into f16x2 pairs (pre-scaled by RSL)
      const float sa0 = a0 * RSL, sa1 = a1 * RSL;
      const float tb0 = __shfl_xor(sa0, 1);
      const float tb1 = __shfl_xor(sa1, 1);
      if ((c & 1) == 0) {
        qT[(n0  )*64 + (c>>1)] = pkh(sa0, tb0);
        qT[(n0+1)*64 + (c>>1)] = pkh(sa1, tb1);
      }
    } else if (mat == 2) {
      // v: pack the two rows (n0, n0+1) per column -> f16x2 (RNE)
      vJ[(n0>>1)*128 + c] = pkrn(a0, a1);
    } else {
      // k: pack adjacent columns via in-wave exchange; grouped layout:
      // kT8[(cb*1024 + n)*8 + slot*2 + wrd], qi=c>>2, cb=qi&7, slot=qi>>3
      const float b0 = __shfl_xor(a0, 1);
      const float b1 = __shfl_xor(a1, 1);
      if ((c & 1) == 0) {
        const int qi = c >> 2, cbv = qi & 7, slot = qi >> 3, wrd = (c >> 1) & 1;
        const int base = (cbv*1024 + n0)*8 + slot*2 + wrd;
        kT8[base]     = pkh(a0, b0);
        kT8[base + 8] = pkh(a1, b1);
      }
    }
  }
  __syncthreads();

  if (t < 256) {
    const int m = t & 63, h = t >> 6;
    const float4* qs4 = (const float4*)qs;
    #pragma unroll
    for (int ii = 0; ii < 2; ++ii) {
      float acc = 0.f;
      #pragma unroll
      for (int ch = 0; ch < 8; ++ch)
        acc += dot4(qs4[ii*32 + h*8 + ch], W2S[m*33 + h*8 + ch]);
      sA[(n0+ii)*328 + 8 + (m>>2)*20 + h*4 + (m&3)] = acc * L2E;
    }
    if (t < 8) {
      const int ii = t >> 2, h2 = t & 3;
      float ca = 0.f;
      #pragma unroll
      for (int d = 0; d < 32; ++d) ca = fmaf(qs[ii*128 + h2*32 + d], b2[h2*32 + d], ca);
      sA[(n0+ii)*328 + h2] = ca * L2E;
    } else if (t < 16) {
      const int tt = t-8, ii = tt>>2, cc = tt&3;
      sA[(n0+ii)*328 + 4 + cc] = (cc < 3) ? pos[(n0+ii)*3 + cc] * L2E : 0.f;
    } else if (t < 24) {
      const int tt = t-16, ii = tt>>2, cc = tt&3;
      pos4w[(n0+ii)*4 + cc] = (cc < 3) ? pos[(n0+ii)*3 + cc] * L2E : 0.f;
    }
  } else if (t < 320) {
    // u: thread = (ii, m-pair); grouped layout: uT4[((mp>>2)*1024 + n)*4 + (mp&3)]
    const int tt = t - 256, ii = tt >> 5, mp = tt & 31;
    const int m0 = mp * 2;
    float ua0 = 0.f, ua1 = 0.f;
    #pragma unroll
    for (int cc = 0; cc < 3; ++cc) {
      const float p = pos[(n0+ii)*3 + cc];
      ua0 = fmaf(p, W1[cc*64 + m0    ], ua0);
      ua1 = fmaf(p, W1[cc*64 + m0 + 1], ua1);
    }
    sA[(n0+ii)*328 + 8 + (m0>>2)*20 + 16 + (m0&3)    ] = ua0 + b1[m0];
    sA[(n0+ii)*328 + 8 + (m0>>2)*20 + 16 + (m0&3) + 1] = ua1 + b1[m0+1];
    uT4[((mp>>2)*1024 + (n0+ii))*4 + (mp&3)] = pack2(ua0, ua1);
  }
}

// ---------------- K2: fused scores + softmax + PV + direct out -------------
// 512 blocks x 1024 thr (16 waves). Block = 2 i-rows x ALL j; wave w = j-tile w.
__global__ __launch_bounds__(1024, 8) void k_attn(
    const unsigned int* __restrict__ qT, const unsigned int* __restrict__ vJ,
    const unsigned int* __restrict__ kT8, const unsigned int* __restrict__ uT4,
    const float* __restrict__ sA, const v4f* __restrict__ pos4,
    float* __restrict__ out)
{
  // e as f16 bits: per wave 8 rows x 80 ushorts (64 used, stride 80 = 40 u32)
  __shared__ __align__(16) unsigned short eH[16*8*80];  // 20.5 KB
  __shared__ __align__(16) float rnum[8192];            // v4f [w][ii][rep][c4]
  __shared__ float rden[128];                           // [w][ii*4+h]

  const int t     = threadIdx.x;
  const int i0    = blockIdx.x * 2;
  const int w     = t >> 6;                    // 0..15 = j-tile
  const int lane  = t & 63;
  const int c4    = lane & 31;
  const int rep   = lane >> 5;
  const int hh    = c4 >> 3;

  const int jb = w*64;
  const int j  = jb + lane;

  const float* sA0 = sA + i0*328;              // uniform -> scalar loads
  const float* sA1 = sA0 + 328;

  const float c00 = sA0[0], c01 = sA0[1], c02 = sA0[2], c03 = sA0[3];
  const float c10 = sA1[0], c11 = sA1[1], c12 = sA1[2], c13 = sA1[3];
  const float p0x = sA0[4], p0y = sA0[5], p0z = sA0[6];
  const float p1x = sA1[4], p1y = sA1[5], p1z = sA1[6];

  const v4f pj = pos4[j];
  const float d0x = p0x-pj.x, d0y = p0y-pj.y, d0z = p0z-pj.z;
  const float d1x = p1x-pj.x, d1y = p1y-pj.y, d1z = p1z-pj.z;
  const float dist0 = sqrtf(d0x*d0x + d0y*d0y + d0z*d0z);
  const float dist1 = sqrtf(d1x*d1x + d1y*d1y + d1z*d1z);

  // ---- geom (packed math, bf16 u stream, uint4-grouped: 8 loads) ----
  v2f g0a={0.f,0.f}, g0b={0.f,0.f}, g0c={0.f,0.f}, g0d={0.f,0.f};
  v2f g1a={0.f,0.f}, g1b={0.f,0.f}, g1c={0.f,0.f}, g1d={0.f,0.f};
  {
    const uint4* ug = (const uint4*)uT4;
#define GEOM_MB(MB, W01, W23) { \
    const v2f uj01 = unpk(W01), uj23 = unpk(W23); \
    const v2f z = {0.f, 0.f}; \
    { \
      const float* ab = sA0 + 8 + (MB)*20; \
      const v2f h01 = __builtin_elementwise_max(*(const v2f*)(ab+16) - uj01, z); \
      const v2f h23 = __builtin_elementwise_max(*(const v2f*)(ab+18) - uj23, z); \
      g0a = fma2(h01, *(const v2f*)(ab+ 0), g0a); g0a = fma2(h23, *(const v2f*)(ab+ 2), g0a); \
      g0b = fma2(h01, *(const v2f*)(ab+ 4), g0b); g0b = fma2(h23, *(const v2f*)(ab+ 6), g0b); \
      g0c = fma2(h01, *(const v2f*)(ab+ 8), g0c); g0c = fma2(h23, *(const v2f*)(ab+10), g0c); \
      g0d = fma2(h01, *(const v2f*)(ab+12), g0d); g0d = fma2(h23, *(const v2f*)(ab+14), g0d); \
    } \
    { \
      const float* ab = sA1 + 8 + (MB)*20; \
      const v2f h01 = __builtin_elementwise_max(*(const v2f*)(ab+16) - uj01, z); \
      const v2f h23 = __builtin_elementwise_max(*(const v2f*)(ab+18) - uj23, z); \
      g1a = fma2(h01, *(const v2f*)(ab+ 0), g1a); g1a = fma2(h23, *(const v2f*)(ab+ 2), g1a); \
      g1b = fma2(h01, *(const v2f*)(ab+ 4), g1b); g1b = fma2(h23, *(const v2f*)(ab+ 6), g1b); \
      g1c = fma2(h01, *(const v2f*)(ab+ 8), g1c); g1c = fma2(h23, *(const v2f*)(ab+10), g1c); \
      g1d = fma2(h01, *(const v2f*)(ab+12), g1d); g1d = fma2(h23, *(const v2f*)(ab+14), g1d); \
    } \
  }
    #pragma unroll 2
    for (int g = 0; g < 8; ++g) {
      const uint4 uw = ug[g*1024 + j];
      GEOM_MB(2*g,     uw.x, uw.y)
      GEOM_MB(2*g + 1, uw.z, uw.w)
    }
#undef GEOM_MB
  }

  // collapse geom v2f accumulators to scalars; qk adds into the scalars
  float t0a = g0a.x + g0a.y, t0b = g0b.x + g0b.y;
  float t0c = g0c.x + g0c.y, t0d = g0d.x + g0d.y;
  float t1a = g1a.x + g1a.y, t1b = g1b.x + g1b.y;
  float t1c = g1c.x + g1c.y, t1d = g1d.x + g1d.y;

  // ---- qk via v_dot2_f32_f16 (grouped kT8: 2 x dwordx4 per cb) ----
  {
    const uint4* kg = (const uint4*)kT8;
    const unsigned int* qT0 = qT + i0*64;
    const unsigned int* qT1 = qT0 + 64;
    #pragma unroll 8
    for (int cb = 0; cb < 8; ++cb) {
      const uint4 ka = kg[(cb*1024 + j)*2];
      const uint4 kb = kg[(cb*1024 + j)*2 + 1];
      t0a = fdot2h(ka.x, qT0[     cb*2], t0a); t0a = fdot2h(ka.y, qT0[     cb*2+1], t0a);
      t0b = fdot2h(ka.z, qT0[16 + cb*2], t0b); t0b = fdot2h(ka.w, qT0[16 + cb*2+1], t0b);
      t0c = fdot2h(kb.x, qT0[32 + cb*2], t0c); t0c = fdot2h(kb.y, qT0[32 + cb*2+1], t0c);
      t0d = fdot2h(kb.z, qT0[48 + cb*2], t0d); t0d = fdot2h(kb.w, qT0[48 + cb*2+1], t0d);
      t1a = fdot2h(ka.x, qT1[     cb*2], t1a); t1a = fdot2h(ka.y, qT1[     cb*2+1], t1a);
      t1b = fdot2h(ka.z, qT1[16 + cb*2], t1b); t1b = fdot2h(ka.w, qT1[16 + cb*2+1], t1b);
      t1c = fdot2h(kb.x, qT1[32 + cb*2], t1c); t1c = fdot2h(kb.y, qT1[32 + cb*2+1], t1c);
      t1d = fdot2h(kb.z, qT1[48 + cb*2], t1d); t1d = fdot2h(kb.w, qT1[48 + cb*2+1], t1d);
    }
  }

  // ---- exp2 numerators: round to f16, store BITS to LDS (b16 writes),
  //      rounded f32 feeds the denominator ----
  float lsum[8];
  unsigned short* eW = &eH[w*640 + lane];
  lsum[0] = e16(exp2f(t0a + (c00 - dist0)), eW        );
  lsum[1] = e16(exp2f(t0b + (c01 - dist0)), eW +  80  );
  lsum[2] = e16(exp2f(t0c + (c02 - dist0)), eW + 160  );
  lsum[3] = e16(exp2f(t0d + (c03 - dist0)), eW + 240  );
  lsum[4] = e16(exp2f(t1a + (c10 - dist1)), eW + 320  );
  lsum[5] = e16(exp2f(t1b + (c11 - dist1)), eW + 400  );
  lsum[6] = e16(exp2f(t1c + (c12 - dist1)), eW + 480  );
  lsum[7] = e16(exp2f(t1d + (c13 - dist1)), eW + 560  );
  __builtin_amdgcn_wave_barrier();

  // ---- denominator reduce first (frees lsum before PV raises pressure) ----
  #pragma unroll
  for (int mm = 1; mm < 64; mm <<= 1) {
    #pragma unroll
    for (int r8 = 0; r8 < 8; ++r8) lsum[r8] += __shfl_xor(lsum[r8], mm);
  }
  if (lane == 0) {
    #pragma unroll
    for (int r8 = 0; r8 < 8; ++r8) rden[w*8 + r8] = lsum[r8];
  }

  // ---- PV: lane owns col-quad c4 (head hh), rep = jp-half of tile.
  //      v f16x2 over j-pairs; e read as packed f16x2 words from eH ----
  v4f acc0 = {0.f,0.f,0.f,0.f};
  v4f acc1 = {0.f,0.f,0.f,0.f};
  {
    const unsigned int* er0 = (const unsigned int*)(eH + (w*8 +     hh)*80) + rep*16;
    const unsigned int* er1 = (const unsigned int*)(eH + (w*8 + 4 + hh)*80) + rep*16;
    const uint4* vg = (const uint4*)vJ + (w*32 + rep*16)*32 + c4;
    #pragma unroll 4
    for (int m = 0; m < 16; ++m) {
      const uint4 vw = vg[m*32];
      const unsigned int e0 = er0[m];
      const unsigned int e1 = er1[m];
      acc0.x = fdot2h(vw.x, e0, acc0.x); acc0.y = fdot2h(vw.y, e0, acc0.y);
      acc0.z = fdot2h(vw.z, e0, acc0.z); acc0.w = fdot2h(vw.w, e0, acc0.w);
      acc1.x = fdot2h(vw.x, e1, acc1.x); acc1.y = fdot2h(vw.y, e1, acc1.y);
      acc1.z = fdot2h(vw.z, e1, acc1.z); acc1.w = fdot2h(vw.w, e1, acc1.w);
    }
  }
  __builtin_amdgcn_wave_barrier();

  // ---- in-block reduce across 16 waves ----
  ((v4f*)rnum)[((w*2+0)*2 + rep)*32 + c4] = acc0;
  ((v4f*)rnum)[((w*2+1)*2 + rep)*32 + c4] = acc1;
  __syncthreads();

  if (t < 256) {
    const int ii = t >> 7, c = t & 127;
    float num = 0.f, den = 0.f;
    #pragma unroll
    for (int ww = 0; ww < 16; ++ww) {
      num += rnum[((ww*2+ii)*2+0)*128 + c];
      num += rnum[((ww*2+ii)*2+1)*128 + c];
      den += rden[ww*8 + ii*4 + (c>>5)];
    }
    out[(i0+ii)*128 + c] = num / den;
  }
}

extern "C" void kernel_launch(void* const* d_in, const int* in_sizes, int n_in,
                              void* d_out, int out_size, void* d_ws, size_t ws_size,
                              hipStream_t stream) {
  const float* x   = (const float*)d_in[0];
  const float* y   = (const float*)d_in[1];
  const float* pos = (const float*)d_in[2];
  const float* Wq  = (const float*)d_in[3];
  const float* bq  = (const float*)d_in[4];
  const float* Wk  = (const float*)d_in[5];
  const float* bk  = (const float*)d_in[6];
  const float* Wv  = (const float*)d_in[7];
  const float* bv  = (const float*)d_in[8];
  const float* W1  = (const float*)d_in[9];
  const float* b1  = (const float*)d_in[10];
  const float* W2  = (const float*)d_in[11];
  const float* b2  = (const float*)d_in[12];

  float* ws = (float*)d_ws;
  unsigned int* qT   = (unsigned int*)ws;               // 65536 u32 (region 131072 f)
  unsigned int* vJ   = (unsigned int*)(ws + 131072);    // 65536 u32 (region 131072 f)
  unsigned int* kT8  = (unsigned int*)(ws + 262144);    // 65536 u32
  unsigned int* uT4  = (unsigned int*)(ws + 327680);    // 32768 u32
  float*        sA   = ws + 360448;                     // 335872
  float*        pos4 = ws + 696320;                     // 4096
  float*        out  = (float*)d_out;

  k_pre<<<dim3(512), dim3(384), 0, stream>>>(x, y, pos, Wq, bq, Wk, bk, Wv, bv,
                                             W1, b1, W2, b2,
                                             qT, vJ, kT8, uT4, sA, pos4);
  k_attn<<<dim3(512), dim3(1024), 0, stream>>>(qT, vJ, kT8, uT4, sA,
                                               (const v4f*)pos4, out);
}